// Round 5
// baseline (1600.587 us; speedup 1.0000x reference)
//
#include <hip/hip_runtime.h>
#include <stdint.h>

// ---------------- types ----------------
typedef __attribute__((ext_vector_type(8))) short bf16x8;   // 8 x bf16 = 4 VGPRs
typedef __attribute__((ext_vector_type(4))) short s16x4;    // 4 x bf16 = 8B
typedef __attribute__((ext_vector_type(4))) float f32x4;
typedef __attribute__((ext_vector_type(4))) unsigned u32x4;
typedef __attribute__((ext_vector_type(2))) unsigned u32x2;

#define AS1 __attribute__((address_space(1)))
#define AS3 __attribute__((address_space(3)))

static __device__ __forceinline__ void gload_lds16(const void* g, void* l) {
  __builtin_amdgcn_global_load_lds((const AS1 unsigned int*)g,
                                   (AS3 unsigned int*)l, 16, 0, 0);
}

// round-to-nearest-even f32 -> bf16 bits
static __device__ __forceinline__ short f2bs(float f) {
  unsigned u = __builtin_bit_cast(unsigned, f);
  unsigned r = (u + 0x7fffu + ((u >> 16) & 1u)) >> 16;
  return (short)r;
}

static __device__ __forceinline__ float sigmoid_f(float x) {
  return 1.0f / (1.0f + __expf(-x));
}
static __device__ __forceinline__ float tanh_f(float x) {
  float ax = fabsf(x);
  float e  = __expf(-2.0f * ax);
  float t  = (1.0f - e) / (1.0f + e);
  return copysignf(t, x);
}

// constants
#define BATCH 256
#define HID   512
#define STEPS 256
#define G3    1536   // 3*HID

// ---------------- fp32 -> bf16 convert (weights) ----------------
__global__ __launch_bounds__(256) void convert_kernel(const float* __restrict__ src,
                                                      short* __restrict__ dst, int n4) {
  int i = blockIdx.x * 256 + threadIdx.x;
  if (i < n4) {
    float4 v = *(const float4*)(src + (size_t)i * 4);
    s16x4 o;
    o[0] = f2bs(v.x); o[1] = f2bs(v.y); o[2] = f2bs(v.z); o[3] = f2bs(v.w);
    *(s16x4*)(dst + (size_t)i * 4) = o;
  }
}

// ---------------- x[b][i][s] f32  ->  xT[s][b][i] bf16 ----------------
__global__ __launch_bounds__(256) void transpose_kernel(const float* __restrict__ x,
                                                        short* __restrict__ xT) {
  int bx = blockIdx.x;
  int st = bx & 7, it = (bx >> 3) & 15, b = bx >> 7;
  int s0 = st * 32, i0 = it * 32;
  int tid = threadIdx.x;
  __shared__ float tile[32][33];
  int il = tid >> 3, s4 = (tid & 7) * 4;
  float4 v = *(const float4*)(x + (size_t)b * 131072 + (size_t)(i0 + il) * 256 + s0 + s4);
  tile[il][s4 + 0] = v.x; tile[il][s4 + 1] = v.y;
  tile[il][s4 + 2] = v.z; tile[il][s4 + 3] = v.w;
  __syncthreads();
  int sl = tid >> 3, iv = (tid & 7) * 4;
  s16x4 o;
  o[0] = f2bs(tile[iv + 0][sl]); o[1] = f2bs(tile[iv + 1][sl]);
  o[2] = f2bs(tile[iv + 2][sl]); o[3] = f2bs(tile[iv + 3][sl]);
  *(s16x4*)(xT + (size_t)(s0 + sl) * 131072 + (size_t)b * 512 + i0 + iv) = o;
}

// ---------------- phase 1: gi[m][g] = xT[m] . W_ih[g] + bias_ih[g] (bf16 out) ----
__global__ __launch_bounds__(256) void phase1_kernel(const short* __restrict__ A,
                                                     const short* __restrict__ B,
                                                     const float* __restrict__ bias,
                                                     short* __restrict__ out, int M) {
  int MT = M >> 7;
  int bx = blockIdx.x;
  int mt = bx % MT, nt = bx / MT;
  int m0 = mt * 128, n0 = nt * 128;
  int tid = threadIdx.x, w = tid >> 6, lane = tid & 63;
  int lm = lane & 15, q = lane >> 4;
  int wm = w & 1, wn = w >> 1;
  __shared__ short As[128 * 32];
  __shared__ short Bs[128 * 32];
  f32x4 acc[4][4] = {};
  int srow = lane >> 2;
  int scol = (lane & 3) * 8;

  for (int kt = 0; kt < 16; ++kt) {
#pragma unroll
    for (int i2 = 0; i2 < 2; ++i2) {
      int i = w * 2 + i2;
      int row = i * 16 + srow;
      gload_lds16(A + (size_t)(m0 + row) * 512 + kt * 32 + scol, As + i * 512);
      gload_lds16(B + (size_t)(n0 + row) * 512 + kt * 32 + scol, Bs + i * 512);
    }
    __syncthreads();
    bf16x8 av[4], bv[4];
#pragma unroll
    for (int f = 0; f < 4; ++f) {
      av[f] = *(const bf16x8*)(As + (wm * 64 + f * 16 + lm) * 32 + q * 8);
      bv[f] = *(const bf16x8*)(Bs + (wn * 64 + f * 16 + lm) * 32 + q * 8);
    }
#pragma unroll
    for (int fm = 0; fm < 4; ++fm)
#pragma unroll
      for (int fn = 0; fn < 4; ++fn)
        acc[fm][fn] = __builtin_amdgcn_mfma_f32_16x16x32_bf16(av[fm], bv[fn], acc[fm][fn], 0, 0, 0);
    __syncthreads();
  }
#pragma unroll
  for (int fn = 0; fn < 4; ++fn) {
    int g = n0 + wn * 64 + fn * 16 + lm;
    float bi = bias[g];
#pragma unroll
    for (int fm = 0; fm < 4; ++fm) {
      int rb = m0 + wm * 64 + fm * 16 + q * 4;
#pragma unroll
      for (int r = 0; r < 4; ++r)
        out[(size_t)(rb + r) * G3 + g] = f2bs(acc[fm][fn][r] + bi);
    }
  }
}

// ---------------- phase 2: persistent GRU scan (tagged-data protocol) --------
// 16 groups (16 batch rows) x 16 gate-slice blocks (96 W_hh rows in regs).
// h exchanged as self-validating dwords: (bf16 << 16) | step_tag. Dword
// atomicity guarantees value/tag consistency; parity double-buffer (same skew
// argument as R2/R4) guarantees no overwrite of a still-needed step. Producers
// store with NO ack and NO flag; consumers poll the data itself until all
// embedded tags == gstep+1. Removes ~2 coherent round-trips per step vs R4.
__global__ __launch_bounds__(256) void scan_kernel(const short* __restrict__ gi,
                                                   const short* __restrict__ Whh,
                                                   const float* __restrict__ bias_hh,
                                                   unsigned* __restrict__ hbuf,
                                                   float* __restrict__ hmaster,
                                                   int CH, int step_base, int first) {
  int bid = blockIdx.x;
  int xcd = bid & 7, slot = bid >> 3;
  int group = xcd + 8 * (slot >> 4);
  int j = slot & 15;
  int tid = threadIdx.x;
  int w = tid >> 6, lane = tid & 63;
  int lm = lane & 15, q = lane >> 4;
  int grow = group * 16;

  int r  = tid >> 4;            // batch row within group (0..15)
  int cs = tid & 15;            // 32-col chunk index == producer block id for poll
  int c0 = cs * 32;             // global col base of this thread's poll slice
  int cp = cs * 2;              // own-slice col pair for elementwise/publish

  __shared__ short h_lds[16 * 520];      // padded rows: 512+8 shorts
  __shared__ float gh_lds[16][100];
  __shared__ float h_loc[512];           // [16][32] own-slice fp32 state
  __shared__ float bhh[96];

  // W_hh slice into registers: wave w (<3) -> gate w, 2 N-tiles of 16
  bf16x8 Bf[2][16];
  if (w < 3) {
#pragma unroll
    for (int tau = 0; tau < 2; ++tau)
#pragma unroll
      for (int kt = 0; kt < 16; ++kt) {
        int row = w * 512 + j * 32 + tau * 16 + lm;
        Bf[tau][kt] = *(const bf16x8*)(Whh + (size_t)row * 512 + kt * 32 + q * 8);
      }
  }

  if (tid < 96) {
    int p = tid >> 5, cc = tid & 31;
    bhh[tid] = bias_hh[p * 512 + j * 32 + cc];
  }

  // initial h(step_base): full rows into h_lds (bf16), own slice into h_loc (fp32)
  if (first) {
#pragma unroll
    for (int c = 0; c < 32; ++c) h_lds[r * 520 + c0 + c] = 0;
    h_loc[2 * tid] = 0.0f; h_loc[2 * tid + 1] = 0.0f;
  } else {
    const float* hm = hmaster + (size_t)(grow + r) * 512 + c0;
#pragma unroll
    for (int c = 0; c < 32; ++c) h_lds[r * 520 + c0 + c] = f2bs(hm[c]);
    const float* ho = hmaster + (size_t)(grow + r) * 512 + j * 32 + cp;
    h_loc[2 * tid] = ho[0]; h_loc[2 * tid + 1] = ho[1];
  }

  // gi prefetch pointers: 1 dword (2 bf16 cols) per gate per thread
  const unsigned* gpu = (const unsigned*)(gi + (size_t)(grow + r) * G3 + j * 32 + cp);
  const size_t gstride_u = (size_t)256 * G3 / 2;   // dwords per step
  unsigned pgr = gpu[0], pgz = gpu[256], pgn = gpu[512];

  __syncthreads();

  for (int tt = 0; tt < CH; ++tt) {
    int gstep = step_base + tt;

    // ---- MFMA: gh[16 x 32] for this wave's gate; 4 independent acc chains ----
    if (w < 3) {
      f32x4 a0 = {0.f,0.f,0.f,0.f}, a1 = {0.f,0.f,0.f,0.f};
      f32x4 a2 = {0.f,0.f,0.f,0.f}, a3 = {0.f,0.f,0.f,0.f};
#pragma unroll
      for (int kt = 0; kt < 8; ++kt) {
        bf16x8 a = *(const bf16x8*)(h_lds + lm * 520 + kt * 32 + q * 8);
        a0 = __builtin_amdgcn_mfma_f32_16x16x32_bf16(a, Bf[0][kt], a0, 0, 0, 0);
        a1 = __builtin_amdgcn_mfma_f32_16x16x32_bf16(a, Bf[1][kt], a1, 0, 0, 0);
      }
#pragma unroll
      for (int kt = 8; kt < 16; ++kt) {
        bf16x8 a = *(const bf16x8*)(h_lds + lm * 520 + kt * 32 + q * 8);
        a2 = __builtin_amdgcn_mfma_f32_16x16x32_bf16(a, Bf[0][kt], a2, 0, 0, 0);
        a3 = __builtin_amdgcn_mfma_f32_16x16x32_bf16(a, Bf[1][kt], a3, 0, 0, 0);
      }
#pragma unroll
      for (int rr = 0; rr < 4; ++rr) {
        gh_lds[q * 4 + rr][w * 32 + lm]      = a0[rr] + a2[rr];
        gh_lds[q * 4 + rr][w * 32 + 16 + lm] = a1[rr] + a3[rr];
      }
    }
    __syncthreads();

    // ---- elementwise GRU cell (pair 2*tid, 2*tid+1 == publish pair) ----
    float gr0 = __builtin_bit_cast(float, pgr << 16);
    float gr1 = __builtin_bit_cast(float, pgr & 0xffff0000u);
    float gz0 = __builtin_bit_cast(float, pgz << 16);
    float gz1 = __builtin_bit_cast(float, pgz & 0xffff0000u);
    float gn0 = __builtin_bit_cast(float, pgn << 16);
    float gn1 = __builtin_bit_cast(float, pgn & 0xffff0000u);

    float hr0 = gh_lds[r][cp]          + bhh[cp];
    float hr1 = gh_lds[r][cp + 1]      + bhh[cp + 1];
    float hz0 = gh_lds[r][32 + cp]     + bhh[32 + cp];
    float hz1 = gh_lds[r][32 + cp + 1] + bhh[32 + cp + 1];
    float hn0 = gh_lds[r][64 + cp]     + bhh[64 + cp];
    float hn1 = gh_lds[r][64 + cp + 1] + bhh[64 + cp + 1];

    float rr0 = sigmoid_f(gr0 + hr0);
    float rr1 = sigmoid_f(gr1 + hr1);
    float zz0 = sigmoid_f(gz0 + hz0);
    float zz1 = sigmoid_f(gz1 + hz1);
    float nn0 = tanh_f(gn0 + rr0 * hn0);
    float nn1 = tanh_f(gn1 + rr1 * hn1);
    float hv0 = (1.0f - zz0) * nn0 + zz0 * h_loc[2 * tid];
    float hv1 = (1.0f - zz1) * nn1 + zz1 * h_loc[2 * tid + 1];
    h_loc[2 * tid]     = hv0;
    h_loc[2 * tid + 1] = hv1;

    // ---- publish own pair: tagged dwords, NO ack, NO flag ----
    unsigned tag = (unsigned)(gstep + 1);
    int p1 = (gstep + 1) & 1;
    {
      unsigned pd0 = ((unsigned)(unsigned short)f2bs(hv0) << 16) | tag;
      unsigned pd1 = ((unsigned)(unsigned short)f2bs(hv1) << 16) | tag;
      u32x2 pd = {pd0, pd1};
      unsigned* hd = hbuf + (size_t)p1 * 131072 + (size_t)(grow + r) * 512 + j * 32 + cp;
      asm volatile("global_store_dwordx2 %0, %1, off sc0 sc1"
                   :: "v"(hd), "v"(pd) : "memory");
    }

    // issue gi prefetch for next step (in flight across the poll)
    {
      size_t o = (size_t)((tt + 1 < CH) ? (tt + 1) : tt) * gstride_u;
      pgr = gpu[o]; pgz = gpu[o + 256]; pgn = gpu[o + 512];
    }
    __syncthreads();   // h_loc complete (self-path readers), gh_lds/h_lds free

    // ---- acquire h(gstep+1): poll tagged data directly ----
    if (tt < CH - 1) {
      if (cs == j) {
        // own block's slice: take from fp32 state (avoids racing own store)
        short* lp = h_lds + r * 520 + c0;
#pragma unroll
        for (int c = 0; c < 32; ++c) lp[c] = f2bs(h_loc[r * 32 + c]);
      } else {
        const unsigned* pb = hbuf + (size_t)p1 * 131072 + (size_t)(grow + r) * 512 + c0;
        u32x4 d0, d1, d2, d3, d4, d5, d6, d7;
        int it = 0;
        while (true) {
          asm volatile(
              "global_load_dwordx4 %0, %8, off sc0 sc1\n\t"
              "global_load_dwordx4 %1, %8, off offset:16 sc0 sc1\n\t"
              "global_load_dwordx4 %2, %8, off offset:32 sc0 sc1\n\t"
              "global_load_dwordx4 %3, %8, off offset:48 sc0 sc1\n\t"
              "global_load_dwordx4 %4, %8, off offset:64 sc0 sc1\n\t"
              "global_load_dwordx4 %5, %8, off offset:80 sc0 sc1\n\t"
              "global_load_dwordx4 %6, %8, off offset:96 sc0 sc1\n\t"
              "global_load_dwordx4 %7, %8, off offset:112 sc0 sc1\n\t"
              "s_waitcnt vmcnt(0)"
              : "=&v"(d0), "=&v"(d1), "=&v"(d2), "=&v"(d3),
                "=&v"(d4), "=&v"(d5), "=&v"(d6), "=&v"(d7)
              : "v"(pb) : "memory");
          unsigned acc =
              (d0[0]^tag)|(d0[1]^tag)|(d0[2]^tag)|(d0[3]^tag)|
              (d1[0]^tag)|(d1[1]^tag)|(d1[2]^tag)|(d1[3]^tag)|
              (d2[0]^tag)|(d2[1]^tag)|(d2[2]^tag)|(d2[3]^tag)|
              (d3[0]^tag)|(d3[1]^tag)|(d3[2]^tag)|(d3[3]^tag)|
              (d4[0]^tag)|(d4[1]^tag)|(d4[2]^tag)|(d4[3]^tag)|
              (d5[0]^tag)|(d5[1]^tag)|(d5[2]^tag)|(d5[3]^tag)|
              (d6[0]^tag)|(d6[1]^tag)|(d6[2]^tag)|(d6[3]^tag)|
              (d7[0]^tag)|(d7[1]^tag)|(d7[2]^tag)|(d7[3]^tag);
          if ((acc & 0xffffu) == 0) break;
          __builtin_amdgcn_s_sleep(1);
          if (++it > (1 << 17)) break;   // bounded: wrong answer beats a hang
        }
        unsigned* lp = (unsigned*)(h_lds + r * 520 + c0);
        lp[0]  = (d0[1] & 0xffff0000u) | (d0[0] >> 16);
        lp[1]  = (d0[3] & 0xffff0000u) | (d0[2] >> 16);
        lp[2]  = (d1[1] & 0xffff0000u) | (d1[0] >> 16);
        lp[3]  = (d1[3] & 0xffff0000u) | (d1[2] >> 16);
        lp[4]  = (d2[1] & 0xffff0000u) | (d2[0] >> 16);
        lp[5]  = (d2[3] & 0xffff0000u) | (d2[2] >> 16);
        lp[6]  = (d3[1] & 0xffff0000u) | (d3[0] >> 16);
        lp[7]  = (d3[3] & 0xffff0000u) | (d3[2] >> 16);
        lp[8]  = (d4[1] & 0xffff0000u) | (d4[0] >> 16);
        lp[9]  = (d4[3] & 0xffff0000u) | (d4[2] >> 16);
        lp[10] = (d5[1] & 0xffff0000u) | (d5[0] >> 16);
        lp[11] = (d5[3] & 0xffff0000u) | (d5[2] >> 16);
        lp[12] = (d6[1] & 0xffff0000u) | (d6[0] >> 16);
        lp[13] = (d6[3] & 0xffff0000u) | (d6[2] >> 16);
        lp[14] = (d7[1] & 0xffff0000u) | (d7[0] >> 16);
        lp[15] = (d7[3] & 0xffff0000u) | (d7[2] >> 16);
      }
    }
    __syncthreads();   // h_lds(gstep+1) ready for next MFMA
  }

  // write fp32 state back (d_out doubles as h_master across chunk launches)
  {
    float* ho = hmaster + (size_t)(grow + r) * 512 + j * 32 + cp;
    ho[0] = h_loc[2 * tid];
    ho[1] = h_loc[2 * tid + 1];
  }
}

// ---------------- host ----------------
extern "C" void kernel_launch(void* const* d_in, const int* in_sizes, int n_in,
                              void* d_out, int out_size, void* d_ws, size_t ws_size,
                              hipStream_t stream) {
  const float* x   = (const float*)d_in[0];
  const float* Wih = (const float*)d_in[1];
  const float* Whh = (const float*)d_in[2];
  const float* bih = (const float*)d_in[3];
  const float* bhh = (const float*)d_in[4];
  float* out = (float*)d_out;
  char* ws = (char*)d_ws;

  const size_t XT_BYTES   = (size_t)256 * 256 * 512 * 2;  // 64 MiB
  const size_t W_BYTES    = (size_t)1536 * 512 * 2;       // 1.5 MiB
  const size_t HBUF_BYTES = (size_t)2 * 256 * 512 * 4;    // 1 MiB (tagged dwords)
  const size_t FIXED = XT_BYTES + 2 * W_BYTES + HBUF_BYTES + 4096;

  int CH = 256;
  while (CH > 4 && FIXED + (size_t)CH * 256 * G3 * 2 > ws_size) CH >>= 1;

  size_t off = 0;
  short* gi = (short*)(ws + off);          off += (size_t)CH * 256 * G3 * 2;
  short* xT = (short*)(ws + off);          off += XT_BYTES;
  short* WihB = (short*)(ws + off);        off += W_BYTES;
  short* WhhB = (short*)(ws + off);        off += W_BYTES;
  unsigned* hbuf = (unsigned*)(ws + off);

  convert_kernel<<<768, 256, 0, stream>>>(Wih, WihB, 196608);
  convert_kernel<<<768, 256, 0, stream>>>(Whh, WhhB, 196608);
  transpose_kernel<<<32768, 256, 0, stream>>>(x, xT);

  int nch = 256 / CH;
  for (int c = 0; c < nch; ++c) {
    int M = CH * 256;
    phase1_kernel<<<(M / 128) * 12, 256, 0, stream>>>(
        xT + (size_t)c * CH * 256 * 512, WihB, bih, gi, M);
    scan_kernel<<<256, 256, 0, stream>>>(gi, WhhB, bhh, hbuf, out,
                                         CH, c * CH, c == 0 ? 1 : 0);
  }
}

// Round 6
// 1072.312 us; speedup vs baseline: 1.4927x; 1.4927x over previous
//
#include <hip/hip_runtime.h>
#include <stdint.h>

// ---------------- types ----------------
typedef __attribute__((ext_vector_type(8))) short bf16x8;   // 8 x bf16 = 4 VGPRs
typedef __attribute__((ext_vector_type(4))) short s16x4;    // 4 x bf16 = 8B
typedef __attribute__((ext_vector_type(4))) float f32x4;
typedef __attribute__((ext_vector_type(4))) unsigned u32x4;
typedef __attribute__((ext_vector_type(2))) unsigned u32x2;

#define AS1 __attribute__((address_space(1)))
#define AS3 __attribute__((address_space(3)))

static __device__ __forceinline__ void gload_lds16(const void* g, void* l) {
  __builtin_amdgcn_global_load_lds((const AS1 unsigned int*)g,
                                   (AS3 unsigned int*)l, 16, 0, 0);
}

// round-to-nearest-even f32 -> bf16 bits
static __device__ __forceinline__ short f2bs(float f) {
  unsigned u = __builtin_bit_cast(unsigned, f);
  unsigned r = (u + 0x7fffu + ((u >> 16) & 1u)) >> 16;
  return (short)r;
}

static __device__ __forceinline__ float sigmoid_f(float x) {
  return 1.0f / (1.0f + __expf(-x));
}
static __device__ __forceinline__ float tanh_f(float x) {
  float ax = fabsf(x);
  float e  = __expf(-2.0f * ax);
  float t  = (1.0f - e) / (1.0f + e);
  return copysignf(t, x);
}

// constants
#define BATCH 256
#define HID   512
#define STEPS 256
#define G3    1536   // 3*HID

// ---------------- fp32 -> bf16 convert (weights) ----------------
__global__ __launch_bounds__(256) void convert_kernel(const float* __restrict__ src,
                                                      short* __restrict__ dst, int n4) {
  int i = blockIdx.x * 256 + threadIdx.x;
  if (i < n4) {
    float4 v = *(const float4*)(src + (size_t)i * 4);
    s16x4 o;
    o[0] = f2bs(v.x); o[1] = f2bs(v.y); o[2] = f2bs(v.z); o[3] = f2bs(v.w);
    *(s16x4*)(dst + (size_t)i * 4) = o;
  }
}

// ---------------- x[b][i][s] f32  ->  xT[s][b][i] bf16 ----------------
__global__ __launch_bounds__(256) void transpose_kernel(const float* __restrict__ x,
                                                        short* __restrict__ xT) {
  int bx = blockIdx.x;
  int st = bx & 7, it = (bx >> 3) & 15, b = bx >> 7;
  int s0 = st * 32, i0 = it * 32;
  int tid = threadIdx.x;
  __shared__ float tile[32][33];
  int il = tid >> 3, s4 = (tid & 7) * 4;
  float4 v = *(const float4*)(x + (size_t)b * 131072 + (size_t)(i0 + il) * 256 + s0 + s4);
  tile[il][s4 + 0] = v.x; tile[il][s4 + 1] = v.y;
  tile[il][s4 + 2] = v.z; tile[il][s4 + 3] = v.w;
  __syncthreads();
  int sl = tid >> 3, iv = (tid & 7) * 4;
  s16x4 o;
  o[0] = f2bs(tile[iv + 0][sl]); o[1] = f2bs(tile[iv + 1][sl]);
  o[2] = f2bs(tile[iv + 2][sl]); o[3] = f2bs(tile[iv + 3][sl]);
  *(s16x4*)(xT + (size_t)(s0 + sl) * 131072 + (size_t)b * 512 + i0 + iv) = o;
}

// ---------------- phase 1: gi[m][g] = xT[m] . W_ih[g] + bias_ih[g] (bf16 out) ----
__global__ __launch_bounds__(256) void phase1_kernel(const short* __restrict__ A,
                                                     const short* __restrict__ B,
                                                     const float* __restrict__ bias,
                                                     short* __restrict__ out, int M) {
  int MT = M >> 7;
  int bx = blockIdx.x;
  int mt = bx % MT, nt = bx / MT;
  int m0 = mt * 128, n0 = nt * 128;
  int tid = threadIdx.x, w = tid >> 6, lane = tid & 63;
  int lm = lane & 15, q = lane >> 4;
  int wm = w & 1, wn = w >> 1;
  __shared__ short As[128 * 32];
  __shared__ short Bs[128 * 32];
  f32x4 acc[4][4] = {};
  int srow = lane >> 2;
  int scol = (lane & 3) * 8;

  for (int kt = 0; kt < 16; ++kt) {
#pragma unroll
    for (int i2 = 0; i2 < 2; ++i2) {
      int i = w * 2 + i2;
      int row = i * 16 + srow;
      gload_lds16(A + (size_t)(m0 + row) * 512 + kt * 32 + scol, As + i * 512);
      gload_lds16(B + (size_t)(n0 + row) * 512 + kt * 32 + scol, Bs + i * 512);
    }
    __syncthreads();
    bf16x8 av[4], bv[4];
#pragma unroll
    for (int f = 0; f < 4; ++f) {
      av[f] = *(const bf16x8*)(As + (wm * 64 + f * 16 + lm) * 32 + q * 8);
      bv[f] = *(const bf16x8*)(Bs + (wn * 64 + f * 16 + lm) * 32 + q * 8);
    }
#pragma unroll
    for (int fm = 0; fm < 4; ++fm)
#pragma unroll
      for (int fn = 0; fn < 4; ++fn)
        acc[fm][fn] = __builtin_amdgcn_mfma_f32_16x16x32_bf16(av[fm], bv[fn], acc[fm][fn], 0, 0, 0);
    __syncthreads();
  }
#pragma unroll
  for (int fn = 0; fn < 4; ++fn) {
    int g = n0 + wn * 64 + fn * 16 + lm;
    float bi = bias[g];
#pragma unroll
    for (int fm = 0; fm < 4; ++fm) {
      int rb = m0 + wm * 64 + fm * 16 + q * 4;
#pragma unroll
      for (int r = 0; r < 4; ++r)
        out[(size_t)(rb + r) * G3 + g] = f2bs(acc[fm][fn][r] + bi);
    }
  }
}

// ---------------- phase 2: persistent GRU scan (coalesced tagged stage-poll) ----
// 16 groups (16 batch rows) x 16 gate-slice blocks (96 W_hh rows).
// h exchanged as self-validating dwords: (bf16 << 16) | step_tag (dword stores
// are atomic -> value/tag always consistent; parity double-buffer prevents
// overwrite of a still-needed step; stale/poison tags can never match).
// Producers publish fire-and-forget (no ack, no flag). Consumers merge
// stage+poll: speculative COALESCED loads (1KB per instruction per wave — the
// R5 regression was scattered 16B coherent loads, 8x the L3 transactions),
// validate all embedded tags, retry until match. h state lives in VGPRs.
__global__ __launch_bounds__(256, 1) void scan_kernel(const short* __restrict__ gi,
                                                      const short* __restrict__ Whh,
                                                      const float* __restrict__ bias_hh,
                                                      unsigned* __restrict__ hbuf,
                                                      float* __restrict__ hmaster,
                                                      int CH, int step_base, int first) {
  int bid = blockIdx.x;
  int xcd = bid & 7, slot = bid >> 3;
  int group = xcd + 8 * (slot >> 4);
  int j = slot & 15;
  int tid = threadIdx.x;
  int w = tid >> 6, lane = tid & 63;
  int lm = lane & 15, q = lane >> 4;
  int grow = group * 16;

  int r  = tid >> 4;            // batch row within group (0..15) for elementwise
  int cp = (tid & 15) * 2;      // own col pair within this block's 32-col slice

  __shared__ short h_lds[16 * 520];      // bf16 h, padded rows (512+8), 16B-aligned rows
  __shared__ float gh_lds[16][101];      // +1 pad: rows alternate bank parity
  __shared__ float bhh[96];

  // W_hh slice into registers: wave w (<3) -> gate w, 2 N-tiles of 16
  bf16x8 Bf[2][16];
  if (w < 3) {
#pragma unroll
    for (int tau = 0; tau < 2; ++tau)
#pragma unroll
      for (int kt = 0; kt < 16; ++kt) {
        int row = w * 512 + j * 32 + tau * 16 + lm;
        Bf[tau][kt] = *(const bf16x8*)(Whh + (size_t)row * 512 + kt * 32 + q * 8);
      }
  }

  if (tid < 96) {
    int p = tid >> 5, cc = tid & 31;
    bhh[tid] = bias_hh[p * 512 + j * 32 + cc];
  }

  // persistent own-pair fp32 state (VGPRs)
  float hv0, hv1;

  // initial h(step_base): h_lds full rows (stage layout: chunk i -> row w*4+(i>>1),
  // col (i&1)*256 + lane*4), own pair into hv regs.
  if (first) {
#pragma unroll
    for (int i = 0; i < 8; ++i) {
      int row = w * 4 + (i >> 1), col = (i & 1) * 256 + lane * 4;
      unsigned* lp = (unsigned*)(h_lds + row * 520 + col);
      lp[0] = 0u; lp[1] = 0u;
    }
    hv0 = 0.0f; hv1 = 0.0f;
  } else {
#pragma unroll
    for (int i = 0; i < 8; ++i) {
      int row = w * 4 + (i >> 1), col = (i & 1) * 256 + lane * 4;
      const float* hm = hmaster + (size_t)(grow + row) * 512 + col;
      s16x4 o;
      o[0] = f2bs(hm[0]); o[1] = f2bs(hm[1]); o[2] = f2bs(hm[2]); o[3] = f2bs(hm[3]);
      *(s16x4*)(h_lds + row * 520 + col) = o;
    }
    const float* ho = hmaster + (size_t)(grow + r) * 512 + j * 32 + cp;
    hv0 = ho[0]; hv1 = ho[1];
  }

  // gi prefetch pointers: 1 dword (2 bf16 cols) per gate per thread
  const unsigned* gpu = (const unsigned*)(gi + (size_t)(grow + r) * G3 + j * 32 + cp);
  const size_t gstride_u = (size_t)256 * G3 / 2;   // dwords per step
  unsigned pgr = gpu[0], pgz = gpu[256], pgn = gpu[512];

  __syncthreads();

  for (int tt = 0; tt < CH; ++tt) {
    int gstep = step_base + tt;
    unsigned tag = (unsigned)(gstep + 1);
    int p1 = (int)(tag & 1u);

    // ---- MFMA: gh[16 x 32] for this wave's gate; 4 independent acc chains ----
    if (w < 3) {
      f32x4 a0 = {0.f,0.f,0.f,0.f}, a1 = {0.f,0.f,0.f,0.f};
      f32x4 a2 = {0.f,0.f,0.f,0.f}, a3 = {0.f,0.f,0.f,0.f};
#pragma unroll
      for (int kt = 0; kt < 8; ++kt) {
        bf16x8 a = *(const bf16x8*)(h_lds + lm * 520 + kt * 32 + q * 8);
        a0 = __builtin_amdgcn_mfma_f32_16x16x32_bf16(a, Bf[0][kt], a0, 0, 0, 0);
        a1 = __builtin_amdgcn_mfma_f32_16x16x32_bf16(a, Bf[1][kt], a1, 0, 0, 0);
      }
#pragma unroll
      for (int kt = 8; kt < 16; ++kt) {
        bf16x8 a = *(const bf16x8*)(h_lds + lm * 520 + kt * 32 + q * 8);
        a2 = __builtin_amdgcn_mfma_f32_16x16x32_bf16(a, Bf[0][kt], a2, 0, 0, 0);
        a3 = __builtin_amdgcn_mfma_f32_16x16x32_bf16(a, Bf[1][kt], a3, 0, 0, 0);
      }
#pragma unroll
      for (int rr = 0; rr < 4; ++rr) {
        gh_lds[q * 4 + rr][w * 32 + lm]      = a0[rr] + a2[rr];
        gh_lds[q * 4 + rr][w * 32 + 16 + lm] = a1[rr] + a3[rr];
      }
    }
    __syncthreads();

    // ---- elementwise GRU cell (own pair, state in VGPRs) ----
    {
      float gr0 = __builtin_bit_cast(float, pgr << 16);
      float gr1 = __builtin_bit_cast(float, pgr & 0xffff0000u);
      float gz0 = __builtin_bit_cast(float, pgz << 16);
      float gz1 = __builtin_bit_cast(float, pgz & 0xffff0000u);
      float gn0 = __builtin_bit_cast(float, pgn << 16);
      float gn1 = __builtin_bit_cast(float, pgn & 0xffff0000u);

      float hr0 = gh_lds[r][cp]          + bhh[cp];
      float hr1 = gh_lds[r][cp + 1]      + bhh[cp + 1];
      float hz0 = gh_lds[r][32 + cp]     + bhh[32 + cp];
      float hz1 = gh_lds[r][32 + cp + 1] + bhh[32 + cp + 1];
      float hn0 = gh_lds[r][64 + cp]     + bhh[64 + cp];
      float hn1 = gh_lds[r][64 + cp + 1] + bhh[64 + cp + 1];

      float rr0 = sigmoid_f(gr0 + hr0);
      float rr1 = sigmoid_f(gr1 + hr1);
      float zz0 = sigmoid_f(gz0 + hz0);
      float zz1 = sigmoid_f(gz1 + hz1);
      float nn0 = tanh_f(gn0 + rr0 * hn0);
      float nn1 = tanh_f(gn1 + rr1 * hn1);
      hv0 = (1.0f - zz0) * nn0 + zz0 * hv0;
      hv1 = (1.0f - zz1) * nn1 + zz1 * hv1;
    }

    if (tt < CH - 1) {
      // ---- publish own pair: tagged dwords, fire-and-forget ----
      {
        unsigned pd0 = ((unsigned)(unsigned short)f2bs(hv0) << 16) | tag;
        unsigned pd1 = ((unsigned)(unsigned short)f2bs(hv1) << 16) | tag;
        u32x2 pd = {pd0, pd1};
        unsigned* hd = hbuf + (size_t)p1 * 131072 + (size_t)(grow + r) * 512 + j * 32 + cp;
        asm volatile("global_store_dwordx2 %0, %1, off sc0 sc1"
                     :: "v"(hd), "v"(pd) : "memory");
      }

      // gi prefetch for next step (in flight across the poll)
      {
        size_t o = (size_t)(tt + 1) * gstride_u;
        pgr = gpu[o]; pgz = gpu[o + 256]; pgn = gpu[o + 512];
      }

      // ---- merged stage+poll: coalesced tagged loads of the whole 32KB group
      // region (1KB per instruction per wave), validate, retry until all 32
      // tags match. Own block's slice self-validates through the same path.
      const unsigned* gb = hbuf + (size_t)p1 * 131072 + (size_t)grow * 512;
      const unsigned* pA = gb + (size_t)w * 2048 + lane * 4;   // chunks 0..3
      const unsigned* pB = pA + 1024;                          // chunks 4..7 (+4KB)
      u32x4 d0, d1, d2, d3, d4, d5, d6, d7;
      int it = 0;
      while (true) {
        asm volatile(
            "global_load_dwordx4 %0, %8, off sc0 sc1\n\t"
            "global_load_dwordx4 %1, %8, off offset:1024 sc0 sc1\n\t"
            "global_load_dwordx4 %2, %8, off offset:2048 sc0 sc1\n\t"
            "global_load_dwordx4 %3, %8, off offset:3072 sc0 sc1\n\t"
            "global_load_dwordx4 %4, %9, off sc0 sc1\n\t"
            "global_load_dwordx4 %5, %9, off offset:1024 sc0 sc1\n\t"
            "global_load_dwordx4 %6, %9, off offset:2048 sc0 sc1\n\t"
            "global_load_dwordx4 %7, %9, off offset:3072 sc0 sc1\n\t"
            "s_waitcnt vmcnt(0)"
            : "=&v"(d0), "=&v"(d1), "=&v"(d2), "=&v"(d3),
              "=&v"(d4), "=&v"(d5), "=&v"(d6), "=&v"(d7)
            : "v"(pA), "v"(pB) : "memory");
        unsigned acc =
            (d0[0]^tag)|(d0[1]^tag)|(d0[2]^tag)|(d0[3]^tag)|
            (d1[0]^tag)|(d1[1]^tag)|(d1[2]^tag)|(d1[3]^tag)|
            (d2[0]^tag)|(d2[1]^tag)|(d2[2]^tag)|(d2[3]^tag)|
            (d3[0]^tag)|(d3[1]^tag)|(d3[2]^tag)|(d3[3]^tag)|
            (d4[0]^tag)|(d4[1]^tag)|(d4[2]^tag)|(d4[3]^tag)|
            (d5[0]^tag)|(d5[1]^tag)|(d5[2]^tag)|(d5[3]^tag)|
            (d6[0]^tag)|(d6[1]^tag)|(d6[2]^tag)|(d6[3]^tag)|
            (d7[0]^tag)|(d7[1]^tag)|(d7[2]^tag)|(d7[3]^tag);
        if ((acc & 0xffffu) == 0u) break;
        __builtin_amdgcn_s_sleep(1);
        if (++it > (1 << 17)) break;   // bounded: wrong answer beats a hang
      }
      // extract bf16 payloads -> h_lds (chunk i -> row w*4+(i>>1), col (i&1)*256+lane*4)
      {
        unsigned* lp;
        int rb = w * 4, cb = lane * 4;
        lp = (unsigned*)(h_lds + (rb + 0) * 520 + cb);
        lp[0] = (d0[1] & 0xffff0000u) | (d0[0] >> 16);
        lp[1] = (d0[3] & 0xffff0000u) | (d0[2] >> 16);
        lp = (unsigned*)(h_lds + (rb + 0) * 520 + 256 + cb);
        lp[0] = (d1[1] & 0xffff0000u) | (d1[0] >> 16);
        lp[1] = (d1[3] & 0xffff0000u) | (d1[2] >> 16);
        lp = (unsigned*)(h_lds + (rb + 1) * 520 + cb);
        lp[0] = (d2[1] & 0xffff0000u) | (d2[0] >> 16);
        lp[1] = (d2[3] & 0xffff0000u) | (d2[2] >> 16);
        lp = (unsigned*)(h_lds + (rb + 1) * 520 + 256 + cb);
        lp[0] = (d3[1] & 0xffff0000u) | (d3[0] >> 16);
        lp[1] = (d3[3] & 0xffff0000u) | (d3[2] >> 16);
        lp = (unsigned*)(h_lds + (rb + 2) * 520 + cb);
        lp[0] = (d4[1] & 0xffff0000u) | (d4[0] >> 16);
        lp[1] = (d4[3] & 0xffff0000u) | (d4[2] >> 16);
        lp = (unsigned*)(h_lds + (rb + 2) * 520 + 256 + cb);
        lp[0] = (d5[1] & 0xffff0000u) | (d5[0] >> 16);
        lp[1] = (d5[3] & 0xffff0000u) | (d5[2] >> 16);
        lp = (unsigned*)(h_lds + (rb + 3) * 520 + cb);
        lp[0] = (d6[1] & 0xffff0000u) | (d6[0] >> 16);
        lp[1] = (d6[3] & 0xffff0000u) | (d6[2] >> 16);
        lp = (unsigned*)(h_lds + (rb + 3) * 520 + 256 + cb);
        lp[0] = (d7[1] & 0xffff0000u) | (d7[0] >> 16);
        lp[1] = (d7[3] & 0xffff0000u) | (d7[2] >> 16);
      }
    }
    __syncthreads();   // h_lds(gstep+1) ready; gh_lds free for next MFMA
  }

  // write fp32 state back (d_out doubles as h_master across chunk launches)
  {
    float* ho = hmaster + (size_t)(grow + r) * 512 + j * 32 + cp;
    ho[0] = hv0;
    ho[1] = hv1;
  }
}

// ---------------- host ----------------
extern "C" void kernel_launch(void* const* d_in, const int* in_sizes, int n_in,
                              void* d_out, int out_size, void* d_ws, size_t ws_size,
                              hipStream_t stream) {
  const float* x   = (const float*)d_in[0];
  const float* Wih = (const float*)d_in[1];
  const float* Whh = (const float*)d_in[2];
  const float* bih = (const float*)d_in[3];
  const float* bhh = (const float*)d_in[4];
  float* out = (float*)d_out;
  char* ws = (char*)d_ws;

  const size_t XT_BYTES   = (size_t)256 * 256 * 512 * 2;  // 64 MiB
  const size_t W_BYTES    = (size_t)1536 * 512 * 2;       // 1.5 MiB
  const size_t HBUF_BYTES = (size_t)2 * 256 * 512 * 4;    // 1 MiB (tagged dwords)
  const size_t FIXED = XT_BYTES + 2 * W_BYTES + HBUF_BYTES + 4096;

  int CH = 256;
  while (CH > 4 && FIXED + (size_t)CH * 256 * G3 * 2 > ws_size) CH >>= 1;

  size_t off = 0;
  short* gi = (short*)(ws + off);          off += (size_t)CH * 256 * G3 * 2;
  short* xT = (short*)(ws + off);          off += XT_BYTES;
  short* WihB = (short*)(ws + off);        off += W_BYTES;
  short* WhhB = (short*)(ws + off);        off += W_BYTES;
  unsigned* hbuf = (unsigned*)(ws + off);

  convert_kernel<<<768, 256, 0, stream>>>(Wih, WihB, 196608);
  convert_kernel<<<768, 256, 0, stream>>>(Whh, WhhB, 196608);
  transpose_kernel<<<32768, 256, 0, stream>>>(x, xT);

  int nch = 256 / CH;
  for (int c = 0; c < nch; ++c) {
    int M = CH * 256;
    phase1_kernel<<<(M / 128) * 12, 256, 0, stream>>>(
        xT + (size_t)c * CH * 256 * 512, WihB, bih, gi, M);
    scan_kernel<<<256, 256, 0, stream>>>(gi, WhhB, bhh, hbuf, out,
                                         CH, c * CH, c == 0 ? 1 : 0);
  }
}